// Round 1
// baseline (439.080 us; speedup 1.0000x reference)
//
#include <hip/hip_runtime.h>
#include <math.h>

#define NB 16          // images
#define NP 100         // predictions per image
#define NT 320         // total targets
#define NCLS 80        // classes
#define WO 128         // output mask width/height
#define HW 16384       // 128*128
#define QT 1600        // NB*NP
#define PI 20          // targets per image
#define KSPLIT 8
#define KSLICE 2048    // HW/KSPLIT
#define SRC_W 256

__device__ __forceinline__ float sigf(float x){ return 1.0f/(1.0f+expf(-x)); }

// jax.image.resize(linear, antialias=True) 2x-downsample weights, 256 -> 128
__device__ __forceinline__ void mkw128(int i, float* w, int* ix){
  int j0 = 2*i - 1;
  ix[0]=j0; ix[1]=j0+1; ix[2]=j0+2; ix[3]=j0+3;
  w[0]=0.125f; w[1]=0.375f; w[2]=0.375f; w[3]=0.125f;
  if (i == 0){ ix[0]=0; w[0]=0.0f; w[1]=3.0f/7.0f; w[2]=3.0f/7.0f; w[3]=1.0f/7.0f; }
  if (i == 127){ ix[3]=255; w[3]=0.0f; w[0]=1.0f/7.0f; w[1]=3.0f/7.0f; w[2]=3.0f/7.0f; }
}

// K1: separable downsample of tgt masks + sum-of-squares per target
__global__ __launch_bounds__(256) void k_downsample(const float* __restrict__ tgt,
                                                    float* __restrict__ tm,
                                                    float* __restrict__ tq){
  const int t = blockIdx.x;
  const int tid = threadIdx.x;
  const float* src = tgt + (size_t)t * (SRC_W*SRC_W);
  __shared__ float hbuf[66*WO];
  __shared__ float wred[4];
  float ssq = 0.f;
  float* dst = tm + (size_t)t * HW;
  for (int c = 0; c < 4; ++c){
    const int base = 64*c - 1;
    __syncthreads();
    for (int e = tid; e < 66*WO; e += 256){
      int lr = e >> 7, ox = e & 127;
      int g = base + lr; g = g < 0 ? 0 : (g > 255 ? 255 : g);
      float w[4]; int ix[4];
      mkw128(ox, w, ix);
      const float* s = src + g*SRC_W;
      hbuf[e] = w[0]*s[ix[0]] + w[1]*s[ix[1]] + w[2]*s[ix[2]] + w[3]*s[ix[3]];
    }
    __syncthreads();
    for (int e = tid; e < 32*WO; e += 256){
      int yo = e >> 7, ox = e & 127;
      int oy = c*32 + yo;
      float w[4]; int iy[4];
      mkw128(oy, w, iy);
      float val = w[0]*hbuf[(iy[0]-base)*WO+ox] + w[1]*hbuf[(iy[1]-base)*WO+ox]
                + w[2]*hbuf[(iy[2]-base)*WO+ox] + w[3]*hbuf[(iy[3]-base)*WO+ox];
      dst[(size_t)oy*WO + ox] = val;
      ssq += val*val;
    }
  }
  for (int off=32; off; off>>=1) ssq += __shfl_xor(ssq, off);
  if ((tid & 63) == 0) wred[tid >> 6] = ssq;
  __syncthreads();
  if (tid == 0) tq[t] = wred[0]+wred[1]+wred[2]+wred[3];
}

// K2: per-query sum of sigmoid(pred_mask)^2
__global__ __launch_bounds__(256) void k_pq(const float* __restrict__ pm, float* __restrict__ pq){
  const int q = blockIdx.x;
  const float4* src = (const float4*)(pm + (size_t)q*HW);
  float s = 0.f;
  #pragma unroll
  for (int i = 0; i < 16; ++i){
    float4 v = src[threadIdx.x + 256*i];
    float a = sigf(v.x), b = sigf(v.y), c = sigf(v.z), d = sigf(v.w);
    s += a*a + b*b + c*c + d*d;
  }
  __shared__ float wred[4];
  for (int off=32; off; off>>=1) s += __shfl_xor(s, off);
  if ((threadIdx.x & 63) == 0) wred[threadIdx.x >> 6] = s;
  __syncthreads();
  if (threadIdx.x == 0) pq[q] = wred[0]+wred[1]+wred[2]+wred[3];
}

// K3: fp32 GEMM  part[s][q][t] = sum_{k in slice s} sigmoid(A[q][k]) * Tm[t][k]
#define BM 64
#define BN 64
#define BK 32
#define LDK 68
__global__ __launch_bounds__(256) void k_gemm(const float* __restrict__ A,
                                              const float* __restrict__ Bm,
                                              float* __restrict__ part){
  __shared__ float As[BK*LDK];
  __shared__ float Bs[BK*LDK];
  const int tid = threadIdx.x;
  const int q0 = blockIdx.x * BM;
  const int t0 = blockIdx.y * BN;
  const int ks = blockIdx.z * KSLICE;
  const int lr = tid >> 3;           // 0..31
  const int lc = (tid & 7) << 2;     // 0..28
  const float* Ap0 = A  + (size_t)(q0+lr   )*HW + ks + lc;
  const float* Ap1 = A  + (size_t)(q0+lr+32)*HW + ks + lc;
  const float* Bp0 = Bm + (size_t)(t0+lr   )*HW + ks + lc;
  const float* Bp1 = Bm + (size_t)(t0+lr+32)*HW + ks + lc;
  const int m0 = (tid & 15) << 2;
  const int n0 = (tid >> 4) << 2;
  float acc[4][4] = {{0.f}};
  for (int kt = 0; kt < KSLICE; kt += BK){
    float4 a0 = *(const float4*)(Ap0 + kt);
    float4 a1 = *(const float4*)(Ap1 + kt);
    float4 b0 = *(const float4*)(Bp0 + kt);
    float4 b1 = *(const float4*)(Bp1 + kt);
    __syncthreads();
    As[(lc+0)*LDK + lr]      = sigf(a0.x);
    As[(lc+1)*LDK + lr]      = sigf(a0.y);
    As[(lc+2)*LDK + lr]      = sigf(a0.z);
    As[(lc+3)*LDK + lr]      = sigf(a0.w);
    As[(lc+0)*LDK + lr + 32] = sigf(a1.x);
    As[(lc+1)*LDK + lr + 32] = sigf(a1.y);
    As[(lc+2)*LDK + lr + 32] = sigf(a1.z);
    As[(lc+3)*LDK + lr + 32] = sigf(a1.w);
    Bs[(lc+0)*LDK + lr]      = b0.x;
    Bs[(lc+1)*LDK + lr]      = b0.y;
    Bs[(lc+2)*LDK + lr]      = b0.z;
    Bs[(lc+3)*LDK + lr]      = b0.w;
    Bs[(lc+0)*LDK + lr + 32] = b1.x;
    Bs[(lc+1)*LDK + lr + 32] = b1.y;
    Bs[(lc+2)*LDK + lr + 32] = b1.z;
    Bs[(lc+3)*LDK + lr + 32] = b1.w;
    __syncthreads();
    #pragma unroll
    for (int kk = 0; kk < BK; ++kk){
      float4 av = *(const float4*)&As[kk*LDK + m0];
      float4 bv = *(const float4*)&Bs[kk*LDK + n0];
      acc[0][0] += av.x*bv.x; acc[0][1] += av.x*bv.y; acc[0][2] += av.x*bv.z; acc[0][3] += av.x*bv.w;
      acc[1][0] += av.y*bv.x; acc[1][1] += av.y*bv.y; acc[1][2] += av.y*bv.z; acc[1][3] += av.y*bv.w;
      acc[2][0] += av.z*bv.x; acc[2][1] += av.z*bv.y; acc[2][2] += av.z*bv.z; acc[2][3] += av.z*bv.w;
      acc[3][0] += av.w*bv.x; acc[3][1] += av.w*bv.y; acc[3][2] += av.w*bv.z; acc[3][3] += av.w*bv.w;
    }
  }
  float* op = part + (size_t)blockIdx.z * (QT*NT) + (size_t)(q0+m0)*NT + t0 + n0;
  #pragma unroll
  for (int i = 0; i < 4; ++i){
    float4 vv = make_float4(acc[i][0], acc[i][1], acc[i][2], acc[i][3]);
    *(float4*)(op + (size_t)i*NT) = vv;
  }
}

// K4: final cost C = dice^0.8 * prob^0.2
__global__ __launch_bounds__(256) void k_cost(const float* __restrict__ part,
                                              const float* __restrict__ pq,
                                              const float* __restrict__ tq,
                                              const float* __restrict__ logits,
                                              const int* __restrict__ ids,
                                              float* __restrict__ Cout){
  int idx = blockIdx.x * 256 + threadIdx.x;
  int q = idx / NT;
  int t = idx - q * NT;
  float num = 0.f;
  #pragma unroll
  for (int s = 0; s < KSPLIT; ++s) num += part[(size_t)s * (QT*NT) + idx];
  num *= 2.0f;
  float den = pq[q] + tq[t] + 1e-4f;
  float dice = num / den;
  float prob = sigf(logits[q * NCLS + ids[t]]);
  Cout[idx] = powf(dice, 0.8f) * powf(prob, 0.2f);
}

// K5: Hungarian (JV / e-maxx with potentials), transposed: 20 rows (targets) x 100 cols (preds).
// One wave (64 lanes) per image; lane owns cols {lane+1, lane+65}; double precision like reference.
__global__ __launch_bounds__(64) void k_hung(const float* __restrict__ C,
                                             float* __restrict__ rows_out,
                                             float* __restrict__ cols_out){
  const int b = blockIdx.x;
  const int lane = threadIdx.x;
  __shared__ float negC[PI*NP];     // [i][j] = -C[b, j, b*PI + i]
  __shared__ double u[PI+1];
  __shared__ int p[NP+1];
  __shared__ int way[NP+1];
  for (int e = lane; e < PI*NP; e += 64){
    int i = e / NP, j = e - i*NP;
    negC[e] = -C[(size_t)(b*NP + j)*NT + (b*PI + i)];
  }
  if (lane <= PI) u[lane] = 0.0;
  for (int j = lane; j <= NP; j += 64){ p[j] = 0; way[j] = 0; }
  __syncthreads();
  const int jA = lane + 1;           // 1..64
  const int jB = lane + 65;          // 65..128
  const bool hasB = (jB <= NP);
  double vA = 0.0, vB = 0.0;
  const double INFD = 1e18;
  for (int i = 1; i <= PI; ++i){
    if (lane == 0) p[0] = i;
    __syncthreads();
    double mvA = INFD, mvB = INFD;
    bool usA = false, usB = false;
    int j0 = 0;
    int jbrk = 0;
    while (true){
      if (jA == j0) usA = true;
      if (hasB && jB == j0) usB = true;
      int i0 = p[j0];
      double ui0 = u[i0];
      double candA = INFD, candB = INFD;
      if (!usA){
        double cur = (double)negC[(i0-1)*NP + (jA-1)] - ui0 - vA;
        if (cur < mvA){ mvA = cur; way[jA] = j0; }
        candA = mvA;
      }
      if (hasB && !usB){
        double cur = (double)negC[(i0-1)*NP + (jB-1)] - ui0 - vB;
        if (cur < mvB){ mvB = cur; way[jB] = j0; }
        candB = mvB;
      }
      double bv; int bj;
      if (candB < candA){ bv = candB; bj = jB; } else { bv = candA; bj = jA; }
      for (int off = 32; off; off >>= 1){
        double ov = __shfl_xor(bv, off);
        int oj = __shfl_xor(bj, off);
        if (ov < bv || (ov == bv && oj < bj)){ bv = ov; bj = oj; }
      }
      const double delta = bv;
      if (usA){ int pj = p[jA]; u[pj] += delta; vA -= delta; }
      else mvA -= delta;
      if (hasB){
        if (usB){ int pj = p[jB]; u[pj] += delta; vB -= delta; }
        else mvB -= delta;
      }
      if (lane == 0) u[p[0]] += delta;   // virtual column 0 carries the new row
      __syncthreads();
      j0 = bj;
      if (p[j0] == 0){ jbrk = j0; break; }
    }
    __syncthreads();
    if (lane == 0){
      int j0a = jbrk;
      while (j0a){
        int jp = way[j0a];
        p[j0a] = p[jp];
        j0a = jp;
      }
    }
    __syncthreads();
  }
  if (lane == 0){
    int cnt = 0;
    for (int j = 1; j <= NP; ++j){
      int pi = p[j];
      if (pi != 0){
        rows_out[b*PI + cnt] = (float)(j - 1);   // prediction index, ascending
        cols_out[b*PI + cnt] = (float)(pi - 1);  // target index within image
        ++cnt;
      }
    }
  }
}

extern "C" void kernel_launch(void* const* d_in, const int* in_sizes, int n_in,
                              void* d_out, int out_size, void* d_ws, size_t ws_size,
                              hipStream_t stream){
  const float* pred_masks  = (const float*)d_in[0];
  const float* pred_logits = (const float*)d_in[1];
  const float* tgt_masks   = (const float*)d_in[2];
  const int*   tgt_ids     = (const int*)d_in[3];
  float* out = (float*)d_out;
  char* ws = (char*)d_ws;
  float* tm   = (float*)ws;                                        // 320*16384 f32 = 20.97 MB
  float* tq   = (float*)(ws + (size_t)NT*HW*4);                    // 320 f32
  float* pq   = (float*)(ws + (size_t)NT*HW*4 + 2048);             // 1600 f32
  float* part = (float*)(ws + (size_t)NT*HW*4 + 2048 + 8192);      // 8*512000 f32 = 16.4 MB

  k_downsample<<<NT, 256, 0, stream>>>(tgt_masks, tm, tq);
  k_pq<<<QT, 256, 0, stream>>>(pred_masks, pq);
  dim3 g(QT/BM, NT/BN, KSPLIT);
  k_gemm<<<g, 256, 0, stream>>>(pred_masks, tm, part);
  k_cost<<<(QT*NT)/256, 256, 0, stream>>>(part, pq, tq, pred_logits, tgt_ids, out);
  k_hung<<<NB, 64, 0, stream>>>(out, out + (size_t)QT*NT, out + (size_t)QT*NT + NT);
}

// Round 2
// 168.927 us; speedup vs baseline: 2.5992x; 2.5992x over previous
//
#include <hip/hip_runtime.h>
#include <math.h>

#define NB 16          // images
#define NP 100         // predictions per image
#define NT 320         // total targets
#define NCLS 80        // classes
#define WO 128         // output mask width/height
#define HW 16384       // 128*128
#define QT 1600        // NB*NP
#define PI 20          // targets per image
#define KSPLIT 8
#define KSLICE 2048    // HW/KSPLIT
#define KTILES 32      // KSLICE/64
#define SRC_W 256
#define BM 64
#define BN 160

typedef _Float16 half4v __attribute__((ext_vector_type(4)));
typedef _Float16 half8v __attribute__((ext_vector_type(8)));
typedef float f32x4 __attribute__((ext_vector_type(4)));

#define GLOAD_LDS16(gp, lp) __builtin_amdgcn_global_load_lds(                         \
    (const __attribute__((address_space(1))) void*)(gp),                              \
    (__attribute__((address_space(3))) void*)(lp), 16, 0, 0)

__device__ __forceinline__ float sigf(float x){ return 1.0f/(1.0f+expf(-x)); }
__device__ __forceinline__ float sigfast(float x){ return 1.0f/(1.0f+__expf(-x)); }

// jax.image.resize(linear, antialias=True) 2x-downsample weights, 256 -> 128
__device__ __forceinline__ void mkw128(int i, float* w, int* ix){
  int j0 = 2*i - 1;
  ix[0]=j0; ix[1]=j0+1; ix[2]=j0+2; ix[3]=j0+3;
  w[0]=0.125f; w[1]=0.375f; w[2]=0.375f; w[3]=0.125f;
  if (i == 0){ ix[0]=0; w[0]=0.0f; w[1]=3.0f/7.0f; w[2]=3.0f/7.0f; w[3]=1.0f/7.0f; }
  if (i == 127){ ix[3]=255; w[3]=0.0f; w[0]=1.0f/7.0f; w[1]=3.0f/7.0f; w[2]=3.0f/7.0f; }
}

// K1: separable downsample of tgt masks (fp16 out) + sum-of-squares per target (fp32)
__global__ __launch_bounds__(256) void k_downsample(const float* __restrict__ tgt,
                                                    _Float16* __restrict__ tm,
                                                    float* __restrict__ tq){
  const int t = blockIdx.x;
  const int tid = threadIdx.x;
  const float* src = tgt + (size_t)t * (SRC_W*SRC_W);
  __shared__ float hbuf[66*WO];
  __shared__ float wred[4];
  float ssq = 0.f;
  _Float16* dst = tm + (size_t)t * HW;
  for (int c = 0; c < 4; ++c){
    const int base = 64*c - 1;
    __syncthreads();
    for (int e = tid; e < 66*WO; e += 256){
      int lr = e >> 7, ox = e & 127;
      int g = base + lr; g = g < 0 ? 0 : (g > 255 ? 255 : g);
      float w[4]; int ix[4];
      mkw128(ox, w, ix);
      const float* s = src + g*SRC_W;
      hbuf[e] = w[0]*s[ix[0]] + w[1]*s[ix[1]] + w[2]*s[ix[2]] + w[3]*s[ix[3]];
    }
    __syncthreads();
    for (int e = tid; e < 32*WO; e += 256){
      int yo = e >> 7, ox = e & 127;
      int oy = c*32 + yo;
      float w[4]; int iy[4];
      mkw128(oy, w, iy);
      float val = w[0]*hbuf[(iy[0]-base)*WO+ox] + w[1]*hbuf[(iy[1]-base)*WO+ox]
                + w[2]*hbuf[(iy[2]-base)*WO+ox] + w[3]*hbuf[(iy[3]-base)*WO+ox];
      dst[(size_t)oy*WO + ox] = (_Float16)val;
      ssq += val*val;
    }
  }
  for (int off=32; off; off>>=1) ssq += __shfl_xor(ssq, off);
  if ((tid & 63) == 0) wred[tid >> 6] = ssq;
  __syncthreads();
  if (tid == 0) tq[t] = wred[0]+wred[1]+wred[2]+wred[3];
}

// K3: MFMA fp16 GEMM  part[z][q][t] = sum_{k in slice z} sigmoid(A[q][k]) * Tm[t][k]
// Fused: sigmoid on A staging, per-row sum sigmoid^2 partials (pqpart).
// Tiles: BM=64 x BN=160 x BK=64; 4 waves, each 32x80 (2x5 16x16x32 frags).
// LDS XOR-swizzle: 16B-chunk index ^= (row&7); B staged by global_load_lds with
// pre-swizzled global source (linear LDS dest), A reg-staged (sigmoid) with
// swizzled ds_write.
__global__ __launch_bounds__(256) void k_gemm(const float* __restrict__ A,
                                              const _Float16* __restrict__ Bm,
                                              float* __restrict__ part,
                                              float* __restrict__ pqpart){
  __shared__ _Float16 As[BM*64];
  __shared__ _Float16 Bs[BN*64];
  const int tid = threadIdx.x;
  const int lane = tid & 63;
  const int wid = tid >> 6;
  const int q0 = blockIdx.x * BM;
  const int t0 = blockIdx.y * BN;
  const int z  = blockIdx.z;
  const int ks = z * KSLICE;

  const int ar = tid >> 2;                 // A-staging row 0..63
  const int ac = (tid & 3) << 4;           // A-staging col 0,16,32,48
  const float* ap = A + (size_t)(q0 + ar) * HW + ks + ac;

  const int wr = wid >> 1, wc = wid & 1;   // wave -> 2x2 sub-tiles of 32x80

  float4 areg[4];
  #pragma unroll
  for (int j = 0; j < 4; ++j) areg[j] = *(const float4*)(ap + j*4);

  f32x4 acc[2][5];
  #pragma unroll
  for (int i = 0; i < 2; ++i)
    #pragma unroll
    for (int n = 0; n < 5; ++n) acc[i][n] = (f32x4){0.f,0.f,0.f,0.f};

  float pqs = 0.f;

  for (int kt = 0; kt < KTILES; ++kt){
    // sigmoid + fp16 cvt + pq accumulation (registers only)
    half4v h[4];
    #pragma unroll
    for (int j = 0; j < 4; ++j){
      float4 v = areg[j];
      float s0 = sigfast(v.x), s1 = sigfast(v.y), s2 = sigfast(v.z), s3 = sigfast(v.w);
      pqs += s0*s0 + s1*s1 + s2*s2 + s3*s3;
      half4v hh = { (_Float16)s0, (_Float16)s1, (_Float16)s2, (_Float16)s3 };
      h[j] = hh;
    }
    __syncthreads();                        // all waves done reading LDS tiles
    // stage B: global_load_lds, linear LDS dest, pre-swizzled global source
    #pragma unroll
    for (int i = 0; i < 5; ++i){
      int g = wid*320 + i*64 + lane;        // 16B chunk id, 1280 total
      int row = g >> 3;
      int cs = (g & 7) ^ (row & 7);
      const _Float16* gp = Bm + (size_t)(t0 + row) * HW + ks + kt*64 + cs*8;
      GLOAD_LDS16(gp, &Bs[(size_t)g * 8]);
    }
    // prefetch next A slice (hidden under compute)
    if (kt + 1 < KTILES){
      #pragma unroll
      for (int j = 0; j < 4; ++j) areg[j] = *(const float4*)(ap + (kt+1)*64 + j*4);
    }
    // stage A: swizzled ds_write_b64
    #pragma unroll
    for (int j = 0; j < 4; ++j){
      int c16 = ((tid & 3) << 1) + (j >> 1);
      int cs = c16 ^ (ar & 7);
      *(half4v*)&As[ar*64 + cs*8 + (j & 1)*4] = h[j];
    }
    __syncthreads();                        // staging (vmcnt+lgkm) drained
    // compute: 2 K-subtiles x (2x5) MFMAs
    #pragma unroll
    for (int s = 0; s < 2; ++s){
      half8v af[2], bf[5];
      int c16 = s*4 + (lane >> 4);
      #pragma unroll
      for (int i = 0; i < 2; ++i){
        int r = wr*32 + i*16 + (lane & 15);
        af[i] = *(const half8v*)&As[r*64 + (c16 ^ (r & 7))*8];
      }
      #pragma unroll
      for (int n = 0; n < 5; ++n){
        int r = wc*80 + n*16 + (lane & 15);
        bf[n] = *(const half8v*)&Bs[r*64 + (c16 ^ (r & 7))*8];
      }
      #pragma unroll
      for (int i = 0; i < 2; ++i)
        #pragma unroll
        for (int n = 0; n < 5; ++n)
          acc[i][n] = __builtin_amdgcn_mfma_f32_16x16x32_f16(af[i], bf[n], acc[i][n], 0, 0, 0);
    }
  }

  // write split-K partials: C/D layout col=lane&15, row=(lane>>4)*4+reg
  float* op = part + (size_t)z * (QT*NT);
  #pragma unroll
  for (int i = 0; i < 2; ++i){
    int qb = q0 + wr*32 + i*16 + (lane >> 4)*4;
    #pragma unroll
    for (int n = 0; n < 5; ++n){
      int t = t0 + wc*80 + n*16 + (lane & 15);
      #pragma unroll
      for (int r = 0; r < 4; ++r)
        op[(size_t)(qb + r)*NT + t] = acc[i][n][r];
    }
  }
  // pq partial: 4 threads per row share (lanes l, l^1, l^2, l^3)
  pqs += __shfl_xor(pqs, 1);
  pqs += __shfl_xor(pqs, 2);
  if ((tid & 3) == 0) pqpart[z*QT + q0 + ar] = pqs;
}

// K4: final cost C = dice^0.8 * prob^0.2 (reduces split-K partials of num and pq)
__global__ __launch_bounds__(256) void k_cost(const float* __restrict__ part,
                                              const float* __restrict__ pqpart,
                                              const float* __restrict__ tq,
                                              const float* __restrict__ logits,
                                              const int* __restrict__ ids,
                                              float* __restrict__ Cout){
  int idx = blockIdx.x * 256 + threadIdx.x;
  int q = idx / NT;
  int t = idx - q * NT;
  float num = 0.f;
  #pragma unroll
  for (int s = 0; s < KSPLIT; ++s) num += part[(size_t)s * (QT*NT) + idx];
  num *= 2.0f;
  float pqv = 0.f;
  #pragma unroll
  for (int s = 0; s < KSPLIT; ++s) pqv += pqpart[s * QT + q];
  float den = pqv + tq[t] + 1e-4f;
  float dice = num / den;
  float prob = sigf(logits[q * NCLS + ids[t]]);
  Cout[idx] = powf(dice, 0.8f) * powf(prob, 0.2f);
}

// K5: Hungarian (JV / e-maxx with potentials), transposed: 20 rows (targets) x 100 cols (preds).
// One wave (64 lanes) per image; lane owns cols {lane+1, lane+65}; double precision like reference.
__global__ __launch_bounds__(64) void k_hung(const float* __restrict__ C,
                                             float* __restrict__ rows_out,
                                             float* __restrict__ cols_out){
  const int b = blockIdx.x;
  const int lane = threadIdx.x;
  __shared__ float negC[PI*NP];     // [i][j] = -C[b, j, b*PI + i]
  __shared__ double u[PI+1];
  __shared__ int p[NP+1];
  __shared__ int way[NP+1];
  for (int e = lane; e < PI*NP; e += 64){
    int i = e / NP, j = e - i*NP;
    negC[e] = -C[(size_t)(b*NP + j)*NT + (b*PI + i)];
  }
  if (lane <= PI) u[lane] = 0.0;
  for (int j = lane; j <= NP; j += 64){ p[j] = 0; way[j] = 0; }
  __syncthreads();
  const int jA = lane + 1;           // 1..64
  const int jB = lane + 65;          // 65..128
  const bool hasB = (jB <= NP);
  double vA = 0.0, vB = 0.0;
  const double INFD = 1e18;
  for (int i = 1; i <= PI; ++i){
    if (lane == 0) p[0] = i;
    __syncthreads();
    double mvA = INFD, mvB = INFD;
    bool usA = false, usB = false;
    int j0 = 0;
    int jbrk = 0;
    while (true){
      if (jA == j0) usA = true;
      if (hasB && jB == j0) usB = true;
      int i0 = p[j0];
      double ui0 = u[i0];
      double candA = INFD, candB = INFD;
      if (!usA){
        double cur = (double)negC[(i0-1)*NP + (jA-1)] - ui0 - vA;
        if (cur < mvA){ mvA = cur; way[jA] = j0; }
        candA = mvA;
      }
      if (hasB && !usB){
        double cur = (double)negC[(i0-1)*NP + (jB-1)] - ui0 - vB;
        if (cur < mvB){ mvB = cur; way[jB] = j0; }
        candB = mvB;
      }
      double bv; int bj;
      if (candB < candA){ bv = candB; bj = jB; } else { bv = candA; bj = jA; }
      for (int off = 32; off; off >>= 1){
        double ov = __shfl_xor(bv, off);
        int oj = __shfl_xor(bj, off);
        if (ov < bv || (ov == bv && oj < bj)){ bv = ov; bj = oj; }
      }
      const double delta = bv;
      if (usA){ int pj = p[jA]; u[pj] += delta; vA -= delta; }
      else mvA -= delta;
      if (hasB){
        if (usB){ int pj = p[jB]; u[pj] += delta; vB -= delta; }
        else mvB -= delta;
      }
      if (lane == 0) u[p[0]] += delta;   // virtual column 0 carries the new row
      __syncthreads();
      j0 = bj;
      if (p[j0] == 0){ jbrk = j0; break; }
    }
    __syncthreads();
    if (lane == 0){
      int j0a = jbrk;
      while (j0a){
        int jp = way[j0a];
        p[j0a] = p[jp];
        j0a = jp;
      }
    }
    __syncthreads();
  }
  if (lane == 0){
    int cnt = 0;
    for (int j = 1; j <= NP; ++j){
      int pi = p[j];
      if (pi != 0){
        rows_out[b*PI + cnt] = (float)(j - 1);   // prediction index, ascending
        cols_out[b*PI + cnt] = (float)(pi - 1);  // target index within image
        ++cnt;
      }
    }
  }
}

extern "C" void kernel_launch(void* const* d_in, const int* in_sizes, int n_in,
                              void* d_out, int out_size, void* d_ws, size_t ws_size,
                              hipStream_t stream){
  const float* pred_masks  = (const float*)d_in[0];
  const float* pred_logits = (const float*)d_in[1];
  const float* tgt_masks   = (const float*)d_in[2];
  const int*   tgt_ids     = (const int*)d_in[3];
  float* out = (float*)d_out;
  char* ws = (char*)d_ws;
  _Float16* Th  = (_Float16*)ws;                                   // 320*16384*2 = 10.49 MB
  float* tq     = (float*)(ws + (size_t)NT*HW*2);                  // 320 f32
  float* pqpart = (float*)(ws + (size_t)NT*HW*2 + 4096);           // 8*1600 f32 = 51.2 KB
  float* part   = (float*)(ws + (size_t)NT*HW*2 + 4096 + 51200);   // 8*512000 f32 = 16.4 MB

  k_downsample<<<NT, 256, 0, stream>>>(tgt_masks, Th, tq);
  dim3 g(QT/BM, NT/BN, KSPLIT);
  k_gemm<<<g, 256, 0, stream>>>(pred_masks, Th, part, pqpart);
  k_cost<<<(QT*NT)/256, 256, 0, stream>>>(part, pqpart, tq, pred_logits, tgt_ids, out);
  k_hung<<<NB, 64, 0, stream>>>(out, out + (size_t)QT*NT, out + (size_t)QT*NT + NT);
}

// Round 3
// 124.790 us; speedup vs baseline: 3.5186x; 1.3537x over previous
//
#include <hip/hip_runtime.h>
#include <math.h>

#define NB 16          // images
#define NP 100         // predictions per image
#define NT 320         // total targets
#define NCLS 80        // classes
#define WO 128         // output mask width/height
#define HW 16384       // 128*128
#define QT 1600        // NB*NP
#define PI 20          // targets per image
#define KSPLIT 8
#define KSLICE 2048    // HW/KSPLIT
#define KTILES 32      // KSLICE/64
#define SRC_W 256
#define BM 64
#define BN 160
#define CH 16          // output rows per downsample block

typedef _Float16 half4v __attribute__((ext_vector_type(4)));
typedef _Float16 half8v __attribute__((ext_vector_type(8)));
typedef float f32x4 __attribute__((ext_vector_type(4)));

#define GLOAD_LDS16(gp, lp) __builtin_amdgcn_global_load_lds(                         \
    (const __attribute__((address_space(1))) void*)(gp),                              \
    (__attribute__((address_space(3))) void*)(lp), 16, 0, 0)

__device__ __forceinline__ float sigf(float x){ return 1.0f/(1.0f+expf(-x)); }
__device__ __forceinline__ float sigfast(float x){ return 1.0f/(1.0f+__expf(-x)); }

// jax.image.resize(linear, antialias=True) 2x-downsample weights, 256 -> 128
__device__ __forceinline__ void mkw128(int i, float* w, int* ix){
  int j0 = 2*i - 1;
  ix[0]=j0; ix[1]=j0+1; ix[2]=j0+2; ix[3]=j0+3;
  w[0]=0.125f; w[1]=0.375f; w[2]=0.375f; w[3]=0.125f;
  if (i == 0){ ix[0]=0; w[0]=0.0f; w[1]=3.0f/7.0f; w[2]=3.0f/7.0f; w[3]=1.0f/7.0f; }
  if (i == 127){ ix[3]=255; w[3]=0.0f; w[0]=1.0f/7.0f; w[1]=3.0f/7.0f; w[2]=3.0f/7.0f; }
}

// K1: separable downsample, one block per (target, 16-row output chunk).
// Stage 1: vertical filter, thread=column, compile-time register indexing.
// Stage 2: horizontal filter from LDS, fp16 store + ssq partial.
__global__ __launch_bounds__(256) void k_downsample(const float* __restrict__ tgt,
                                                    _Float16* __restrict__ tm,
                                                    float* __restrict__ tqpart){
  const int blk = blockIdx.x;
  const int t = blk >> 3;
  const int c = blk & 7;               // chunk: output rows [c*16, c*16+16)
  const int x = threadIdx.x;           // input column 0..255
  const int oy0 = c * CH;
  const int r0 = 2*oy0 - 1;            // first needed input row (may be -1)
  const float* src = tgt + (size_t)t * (SRC_W*SRC_W);
  __shared__ float vbuf[CH][SRC_W];
  __shared__ float wred[4];

  float cc[34];
  #pragma unroll
  for (int li = 0; li < 34; ++li){
    int r = r0 + li; r = r < 0 ? 0 : (r > 255 ? 255 : r);
    cc[li] = src[r*SRC_W + x];
  }
  #pragma unroll
  for (int dy = 0; dy < CH; ++dy){
    int oy = oy0 + dy;
    float w0=0.125f, w1=0.375f, w2=0.375f, w3=0.125f;
    if (oy == 0){ w0=0.0f; w1=3.0f/7.0f; w2=3.0f/7.0f; w3=1.0f/7.0f; }
    if (oy == 127){ w3=0.0f; w0=1.0f/7.0f; w1=3.0f/7.0f; w2=3.0f/7.0f; }
    vbuf[dy][x] = w0*cc[2*dy] + w1*cc[2*dy+1] + w2*cc[2*dy+2] + w3*cc[2*dy+3];
  }
  __syncthreads();

  float ssq = 0.f;
  _Float16* dst = tm + (size_t)t * HW + (size_t)oy0 * WO;
  #pragma unroll
  for (int i = 0; i < 8; ++i){
    int e = x + 256*i;                 // 0..2047
    int oy = e >> 7;                   // local output row 0..15
    int ox = e & 127;
    float w[4]; int ix[4];
    mkw128(ox, w, ix);
    float val = w[0]*vbuf[oy][ix[0]] + w[1]*vbuf[oy][ix[1]]
              + w[2]*vbuf[oy][ix[2]] + w[3]*vbuf[oy][ix[3]];
    dst[oy*WO + ox] = (_Float16)val;
    ssq += val*val;
  }
  for (int off=32; off; off>>=1) ssq += __shfl_xor(ssq, off);
  if ((x & 63) == 0) wred[x >> 6] = ssq;
  __syncthreads();
  if (x == 0) tqpart[c*NT + t] = wred[0]+wred[1]+wred[2]+wred[3];
}

// K3: MFMA fp16 GEMM  part[z][q][t] = sum_{k in slice z} sigmoid(A[q][k]) * Tm[t][k]
__global__ __launch_bounds__(256) void k_gemm(const float* __restrict__ A,
                                              const _Float16* __restrict__ Bm,
                                              float* __restrict__ part,
                                              float* __restrict__ pqpart){
  __shared__ _Float16 As[BM*64];
  __shared__ _Float16 Bs[BN*64];
  const int tid = threadIdx.x;
  const int lane = tid & 63;
  const int wid = tid >> 6;
  const int q0 = blockIdx.x * BM;
  const int t0 = blockIdx.y * BN;
  const int z  = blockIdx.z;
  const int ks = z * KSLICE;

  const int ar = tid >> 2;                 // A-staging row 0..63
  const int ac = (tid & 3) << 4;           // A-staging col 0,16,32,48
  const float* ap = A + (size_t)(q0 + ar) * HW + ks + ac;

  const int wr = wid >> 1, wc = wid & 1;   // wave -> 2x2 sub-tiles of 32x80

  float4 areg[4];
  #pragma unroll
  for (int j = 0; j < 4; ++j) areg[j] = *(const float4*)(ap + j*4);

  f32x4 acc[2][5];
  #pragma unroll
  for (int i = 0; i < 2; ++i)
    #pragma unroll
    for (int n = 0; n < 5; ++n) acc[i][n] = (f32x4){0.f,0.f,0.f,0.f};

  float pqs = 0.f;

  for (int kt = 0; kt < KTILES; ++kt){
    half4v h[4];
    #pragma unroll
    for (int j = 0; j < 4; ++j){
      float4 v = areg[j];
      float s0 = sigfast(v.x), s1 = sigfast(v.y), s2 = sigfast(v.z), s3 = sigfast(v.w);
      pqs += s0*s0 + s1*s1 + s2*s2 + s3*s3;
      half4v hh = { (_Float16)s0, (_Float16)s1, (_Float16)s2, (_Float16)s3 };
      h[j] = hh;
    }
    __syncthreads();                        // all waves done reading LDS tiles
    #pragma unroll
    for (int i = 0; i < 5; ++i){
      int g = wid*320 + i*64 + lane;        // 16B chunk id, 1280 total
      int row = g >> 3;
      int cs = (g & 7) ^ (row & 7);
      const _Float16* gp = Bm + (size_t)(t0 + row) * HW + ks + kt*64 + cs*8;
      GLOAD_LDS16(gp, &Bs[(size_t)g * 8]);
    }
    if (kt + 1 < KTILES){
      #pragma unroll
      for (int j = 0; j < 4; ++j) areg[j] = *(const float4*)(ap + (kt+1)*64 + j*4);
    }
    #pragma unroll
    for (int j = 0; j < 4; ++j){
      int c16 = ((tid & 3) << 1) + (j >> 1);
      int cs = c16 ^ (ar & 7);
      *(half4v*)&As[ar*64 + cs*8 + (j & 1)*4] = h[j];
    }
    __syncthreads();                        // staging (vmcnt+lgkm) drained
    #pragma unroll
    for (int s = 0; s < 2; ++s){
      half8v af[2], bf[5];
      int c16 = s*4 + (lane >> 4);
      #pragma unroll
      for (int i = 0; i < 2; ++i){
        int r = wr*32 + i*16 + (lane & 15);
        af[i] = *(const half8v*)&As[r*64 + (c16 ^ (r & 7))*8];
      }
      #pragma unroll
      for (int n = 0; n < 5; ++n){
        int r = wc*80 + n*16 + (lane & 15);
        bf[n] = *(const half8v*)&Bs[r*64 + (c16 ^ (r & 7))*8];
      }
      #pragma unroll
      for (int i = 0; i < 2; ++i)
        #pragma unroll
        for (int n = 0; n < 5; ++n)
          acc[i][n] = __builtin_amdgcn_mfma_f32_16x16x32_f16(af[i], bf[n], acc[i][n], 0, 0, 0);
    }
  }

  float* op = part + (size_t)z * (QT*NT);
  #pragma unroll
  for (int i = 0; i < 2; ++i){
    int qb = q0 + wr*32 + i*16 + (lane >> 4)*4;
    #pragma unroll
    for (int n = 0; n < 5; ++n){
      int t = t0 + wc*80 + n*16 + (lane & 15);
      #pragma unroll
      for (int r = 0; r < 4; ++r)
        op[(size_t)(qb + r)*NT + t] = acc[i][n][r];
    }
  }
  pqs += __shfl_xor(pqs, 1);
  pqs += __shfl_xor(pqs, 2);
  if ((tid & 3) == 0) pqpart[z*QT + q0 + ar] = pqs;
}

// K4: final cost C = dice^0.8 * prob^0.2 (reduces split-K partials of num, pq, tq)
__global__ __launch_bounds__(256) void k_cost(const float* __restrict__ part,
                                              const float* __restrict__ pqpart,
                                              const float* __restrict__ tqpart,
                                              const float* __restrict__ logits,
                                              const int* __restrict__ ids,
                                              float* __restrict__ Cout){
  int idx = blockIdx.x * 256 + threadIdx.x;
  int q = idx / NT;
  int t = idx - q * NT;
  float num = 0.f;
  #pragma unroll
  for (int s = 0; s < KSPLIT; ++s) num += part[(size_t)s * (QT*NT) + idx];
  num *= 2.0f;
  float pqv = 0.f;
  #pragma unroll
  for (int s = 0; s < KSPLIT; ++s) pqv += pqpart[s * QT + q];
  float tqv = 0.f;
  #pragma unroll
  for (int s = 0; s < 8; ++s) tqv += tqpart[s * NT + t];
  float den = pqv + tqv + 1e-4f;
  float dice = num / den;
  float prob = sigf(logits[q * NCLS + ids[t]]);
  Cout[idx] = powf(dice, 0.8f) * powf(prob, 0.2f);
}

// K5: Hungarian (JV / e-maxx with potentials), transposed: 20 rows (targets) x 100 cols (preds).
__global__ __launch_bounds__(64) void k_hung(const float* __restrict__ C,
                                             float* __restrict__ rows_out,
                                             float* __restrict__ cols_out){
  const int b = blockIdx.x;
  const int lane = threadIdx.x;
  __shared__ float negC[PI*NP];     // [i][j] = -C[b, j, b*PI + i]
  __shared__ double u[PI+1];
  __shared__ int p[NP+1];
  __shared__ int way[NP+1];
  for (int e = lane; e < PI*NP; e += 64){
    int i = e / NP, j = e - i*NP;
    negC[e] = -C[(size_t)(b*NP + j)*NT + (b*PI + i)];
  }
  if (lane <= PI) u[lane] = 0.0;
  for (int j = lane; j <= NP; j += 64){ p[j] = 0; way[j] = 0; }
  __syncthreads();
  const int jA = lane + 1;           // 1..64
  const int jB = lane + 65;          // 65..128
  const bool hasB = (jB <= NP);
  double vA = 0.0, vB = 0.0;
  const double INFD = 1e18;
  for (int i = 1; i <= PI; ++i){
    if (lane == 0) p[0] = i;
    __syncthreads();
    double mvA = INFD, mvB = INFD;
    bool usA = false, usB = false;
    int j0 = 0;
    int jbrk = 0;
    while (true){
      if (jA == j0) usA = true;
      if (hasB && jB == j0) usB = true;
      int i0 = p[j0];
      double ui0 = u[i0];
      double candA = INFD, candB = INFD;
      if (!usA){
        double cur = (double)negC[(i0-1)*NP + (jA-1)] - ui0 - vA;
        if (cur < mvA){ mvA = cur; way[jA] = j0; }
        candA = mvA;
      }
      if (hasB && !usB){
        double cur = (double)negC[(i0-1)*NP + (jB-1)] - ui0 - vB;
        if (cur < mvB){ mvB = cur; way[jB] = j0; }
        candB = mvB;
      }
      double bv; int bj;
      if (candB < candA){ bv = candB; bj = jB; } else { bv = candA; bj = jA; }
      for (int off = 32; off; off >>= 1){
        double ov = __shfl_xor(bv, off);
        int oj = __shfl_xor(bj, off);
        if (ov < bv || (ov == bv && oj < bj)){ bv = ov; bj = oj; }
      }
      const double delta = bv;
      if (usA){ int pj = p[jA]; u[pj] += delta; vA -= delta; }
      else mvA -= delta;
      if (hasB){
        if (usB){ int pj = p[jB]; u[pj] += delta; vB -= delta; }
        else mvB -= delta;
      }
      if (lane == 0) u[p[0]] += delta;   // virtual column 0 carries the new row
      __syncthreads();
      j0 = bj;
      if (p[j0] == 0){ jbrk = j0; break; }
    }
    __syncthreads();
    if (lane == 0){
      int j0a = jbrk;
      while (j0a){
        int jp = way[j0a];
        p[j0a] = p[jp];
        j0a = jp;
      }
    }
    __syncthreads();
  }
  if (lane == 0){
    int cnt = 0;
    for (int j = 1; j <= NP; ++j){
      int pi = p[j];
      if (pi != 0){
        rows_out[b*PI + cnt] = (float)(j - 1);   // prediction index, ascending
        cols_out[b*PI + cnt] = (float)(pi - 1);  // target index within image
        ++cnt;
      }
    }
  }
}

extern "C" void kernel_launch(void* const* d_in, const int* in_sizes, int n_in,
                              void* d_out, int out_size, void* d_ws, size_t ws_size,
                              hipStream_t stream){
  const float* pred_masks  = (const float*)d_in[0];
  const float* pred_logits = (const float*)d_in[1];
  const float* tgt_masks   = (const float*)d_in[2];
  const int*   tgt_ids     = (const int*)d_in[3];
  float* out = (float*)d_out;
  char* ws = (char*)d_ws;
  _Float16* Th  = (_Float16*)ws;                                   // 320*16384*2 = 10.49 MB
  float* tqpart = (float*)(ws + (size_t)NT*HW*2);                  // 8*320 f32 = 10.24 KB
  float* pqpart = (float*)(ws + (size_t)NT*HW*2 + 16384);          // 8*1600 f32 = 51.2 KB
  float* part   = (float*)(ws + (size_t)NT*HW*2 + 16384 + 65536);  // 8*512000 f32 = 16.4 MB

  k_downsample<<<NT*8, 256, 0, stream>>>(tgt_masks, Th, tqpart);
  dim3 g(QT/BM, NT/BN, KSPLIT);
  k_gemm<<<g, 256, 0, stream>>>(pred_masks, Th, part, pqpart);
  k_cost<<<(QT*NT)/256, 256, 0, stream>>>(part, pqpart, tqpart, pred_logits, tgt_ids, out);
  k_hung<<<NB, 64, 0, stream>>>(out, out + (size_t)QT*NT, out + (size_t)QT*NT + NT);
}